// Round 14
// baseline (202.313 us; speedup 1.0000x reference)
//
#include <hip/hip_runtime.h>

#define N_NODES 50000
#define N_EDGES 800000
#define D 64
#define COARSE 196           // coarse bins of 256 nodes (tgt>>8)
#define SHARDS 16            // reservation shards per bin (block b -> b&15)
#define SCAP 384             // per (bin,shard) capacity: mean 255 + 8 sigma
#define BINS 3125            // k2 bins of 16 nodes
#define BIN_NODES 16
#define NODE_CAP 64          // deg ~ Poisson(16); P(>64) ~ 1e-18
#define BROW 72              // u16 stride per node bucket in LDS (144 B)
#define KA_BLOCKS 391        // 2048 edges per block (last: 1280)
#define KA_EDGES 2048
#define GEMV_BLOCKS 3125
#define CVT_BLOCKS 3125
#define K1_BLOCKS (KA_BLOCKS + GEMV_BLOCKS + CVT_BLOCKS)

__device__ __forceinline__ unsigned int f2bf(float f) {
    unsigned int u = __builtin_bit_cast(unsigned int, f);
    return (u + 0x7fffu + ((u >> 16) & 1u)) >> 16;
}
__device__ __forceinline__ float bflo(unsigned int v) {
    return __builtin_bit_cast(float, v << 16);
}
__device__ __forceinline__ float bfhi(unsigned int v) {
    return __builtin_bit_cast(float, v & 0xffff0000u);
}

// ---------------------------------------------------------------------------
// K1: three roles, ROLE-MAJOR (R12 lesson: long-pole KA blocks must all start
// at t=0; short CVT/GEMV blocks backfill).
//  [0, KA): coarse binning. R13's wall theory: 76K device-scope atomicAdds
//    onto 196 counters -> ~391-deep serial RMW queue per counter (~30 us).
//    Fix: 16 SHARD counters per bin; block b reserves from shard b&15 in a
//    FIXED per-shard segment of gPairs -> queues 16x shorter.
//  [KA,+GEMV): out = merge @ W_tr^T + b_tr   (direct to d_out; k2 RMWs it)
//  [..,+CVT):  data16 = bf16(data), RNE, coalesced.
// ---------------------------------------------------------------------------
__global__ __launch_bounds__(256) void k1_kernel(
        const float* __restrict__ data,
        const float* __restrict__ merge,
        const int* __restrict__ src, const int* __restrict__ tgt,
        const float* __restrict__ W_tr, const float* __restrict__ b_tr,
        unsigned short* __restrict__ data16,
        int* __restrict__ gCur, unsigned int* __restrict__ gPairs,
        float* __restrict__ outv) {
    int b = blockIdx.x;
    int tid = threadIdx.x;
    if (b < KA_BLOCKS) {
        __shared__ unsigned int epair[KA_EDGES];
        __shared__ int hist[COARSE], rbase[COARSE], cur2[COARSE];
        int eb = b * KA_EDGES;
        int n = N_EDGES - eb; if (n > KA_EDGES) n = KA_EDGES;
        int shard = b & (SHARDS - 1);
        if (tid < COARSE) { hist[tid] = 0; cur2[tid] = 0; }
        __syncthreads();
        // phase 1: stage + hist (vectorized: 2 edges/thread/iter)
        for (int i0 = tid * 2; i0 < n; i0 += 512) {
            uint2 tv = *(const uint2*)(tgt + eb + i0);
            uint2 sv = *(const uint2*)(src + eb + i0);
            unsigned int p0 = (tv.x << 16) | sv.x;
            unsigned int p1 = (tv.y << 16) | sv.y;
            epair[i0] = p0;
            epair[i0 + 1] = p1;
            atomicAdd(&hist[tv.x >> 8], 1);
            atomicAdd(&hist[tv.y >> 8], 1);
        }
        __syncthreads();
        // phase 2: sharded reservation (queue depth ~24 instead of ~391)
        if (tid < COARSE && hist[tid] > 0)
            rbase[tid] = atomicAdd(&gCur[tid * SHARDS + shard], hist[tid]);
        __syncthreads();
        // phase 3: scatter into this block's reserved run in shard segment
        size_t segBase0 = (size_t)shard * SCAP;
        for (int i = tid; i < n; i += 256) {
            unsigned int p = epair[i];
            int c = p >> 24;                        // tgt>>8
            int pos = rbase[c] + atomicAdd(&cur2[c], 1);
            if (pos < SCAP)
                gPairs[(size_t)c * (SHARDS * SCAP) + segBase0 + pos] = p;
        }
    } else if (b < KA_BLOCKS + GEMV_BLOCKS) {
        int gb = b - KA_BLOCKS;
        int lane = tid & 63;
        int slot = tid >> 6;
        float4 Wr[16];
        const float4* wrow = (const float4*)(W_tr + (size_t)lane * D);
#pragma unroll
        for (int i = 0; i < 16; i++) Wr[i] = wrow[i];
        float bias = b_tr[lane];
        const int stride = GEMV_BLOCKS * 4;
        int r = gb * 4 + slot;
        float rv = merge[(size_t)r * D + lane];
        while (r < N_NODES) {
            int rn = r + stride;
            float rv_next = 0.f;
            if (rn < N_NODES) rv_next = merge[(size_t)rn * D + lane];
            float a0 = 0.f, a1 = 0.f, a2 = 0.f, a3 = 0.f;
#pragma unroll
            for (int i = 0; i < 16; i++) {
                a0 += __shfl(rv, 4 * i)     * Wr[i].x;
                a1 += __shfl(rv, 4 * i + 1) * Wr[i].y;
                a2 += __shfl(rv, 4 * i + 2) * Wr[i].z;
                a3 += __shfl(rv, 4 * i + 3) * Wr[i].w;
            }
            outv[(size_t)r * D + lane] = ((a0 + a1) + (a2 + a3)) + bias;
            rv = rv_next;
            r = rn;
        }
    } else {
        int i = (b - KA_BLOCKS - GEMV_BLOCKS) * 256 + tid;   // float4 index
        float4 d = ((const float4*)data)[i];
        uint2 v;
        v.x = f2bf(d.x) | (f2bf(d.y) << 16);
        v.y = f2bf(d.z) | (f2bf(d.w) << 16);
        ((uint2*)data16)[i] = v;
    }
}

// ---------------------------------------------------------------------------
// FILL: one block per coarse bin (256 nodes). Sweep the bin's 16 shard
// segments (base+count from gCur) and scatter into per-node GLOBAL buckets
// srcs16[node*64] + deg[node]. One block owns its 32 KB bucket region for
// its whole lifetime -> lines fill while L2-hot (R13-verified clean writes).
// ---------------------------------------------------------------------------
__global__ __launch_bounds__(256) void fill_kernel(
        const int* __restrict__ gCur,
        const unsigned int* __restrict__ gPairs,
        unsigned short* __restrict__ srcs16,
        int* __restrict__ deg) {
    __shared__ int lcur[256];
    int c = blockIdx.x;
    int tid = threadIdx.x;
    lcur[tid] = 0;
    __syncthreads();
    for (int s = 0; s < SHARDS; s++) {
        int cnt = gCur[c * SHARDS + s]; if (cnt > SCAP) cnt = SCAP;
        const unsigned int* cp = gPairs + (size_t)c * (SHARDS * SCAP)
                                        + (size_t)s * SCAP;
        for (int i = tid; i < cnt; i += 256) {
            unsigned int p = cp[i];
            int tl = (p >> 16) & 255;        // local node within coarse bin
            int pos = atomicAdd(&lcur[tl], 1);
            if (pos < NODE_CAP)
                srcs16[((size_t)c * 256 + tl) * NODE_CAP + pos] =
                    (unsigned short)(p & 0xffffu);
        }
    }
    __syncthreads();
    int node = c * 256 + tid;
    if (node < N_NODES) deg[node] = lcur[tid];
}

// ---------------------------------------------------------------------------
// K2: one block per 16-node bin (unchanged from R13 -- known-good).
//  1. stage the 16 buckets (2 KB coalesced) + deg into LDS.
//  2. gather: 8-lane group per (node, parity); lane owns cols 8l..8l+7,
//     uint4 loads -> one wave-instr fetches 8 rows (1 KB); indices from LDS
//     broadcast. 4 chains/group.
//  3. parity halves combined via shfl_xor(8); h to LDS.
//  4. fused GEMV: out = relu(h @ W_lin^T + out)  (out holds merge-GEMV).
// ---------------------------------------------------------------------------
__global__ __launch_bounds__(256) void k2_kernel(
        const float* __restrict__ data,
        const unsigned short* __restrict__ data16,
        const unsigned short* __restrict__ srcs16,
        const int* __restrict__ deg,
        const float* __restrict__ W_lin,
        float* __restrict__ out) {
    __shared__ __align__(16) unsigned short lbkt[BIN_NODES * BROW];  // 2.25 KB
    __shared__ int lcur[BIN_NODES];
    __shared__ float hbuf[BIN_NODES * D];                            // 4 KB

    int tid = threadIdx.x;
    int lane = tid & 63;
    int bin = blockIdx.x;
    int nodeBase = bin * BIN_NODES;

    float4 Wr[16];
    const float4* wrow = (const float4*)(W_lin + (size_t)lane * D);
#pragma unroll
    for (int i = 0; i < 16; i++) Wr[i] = wrow[i];

    {
        int node = tid >> 4;
        int ln = tid & 15;
        uint2 w = ((const uint2*)(srcs16 + ((size_t)nodeBase + node) * NODE_CAP))[ln];
        ((uint2*)(lbkt + node * BROW))[ln] = w;
        if (tid < BIN_NODES) lcur[tid] = deg[nodeBase + tid];
    }
    __syncthreads();

    int G = tid >> 3;
    int ln = tid & 7;
    int node = G >> 1;
    int par = G & 1;
    int n = nodeBase + node;
    int dg = lcur[node];
    int dgc = dg < NODE_CAP ? dg : NODE_CAP;

    const float4* orow = (const float4*)(data + (size_t)n * D + 8 * ln);
    float4 o0 = orow[0], o1 = orow[1];

    float a0[8] = {0,0,0,0,0,0,0,0}, a1[8] = {0,0,0,0,0,0,0,0};
    float a2[8] = {0,0,0,0,0,0,0,0}, a3[8] = {0,0,0,0,0,0,0,0};
    const uint2* idxp = (const uint2*)(lbkt + node * BROW + par * 4);
    int nIt = (dgc + 7) >> 3;
    for (int it = 0; it < nIt; it++) {
        uint2 iw = idxp[it * 2];
        int e0 = it * 8 + par * 4;
        unsigned int i0 = iw.x & 0xffffu, i1 = iw.x >> 16;
        unsigned int i2 = iw.y & 0xffffu, i3 = iw.y >> 16;
        if (e0 < dgc) {
            uint4 v = *(const uint4*)(data16 + (size_t)i0 * D + 8 * ln);
            a0[0] += bflo(v.x); a0[1] += bfhi(v.x); a0[2] += bflo(v.y); a0[3] += bfhi(v.y);
            a0[4] += bflo(v.z); a0[5] += bfhi(v.z); a0[6] += bflo(v.w); a0[7] += bfhi(v.w);
        }
        if (e0 + 1 < dgc) {
            uint4 v = *(const uint4*)(data16 + (size_t)i1 * D + 8 * ln);
            a1[0] += bflo(v.x); a1[1] += bfhi(v.x); a1[2] += bflo(v.y); a1[3] += bfhi(v.y);
            a1[4] += bflo(v.z); a1[5] += bfhi(v.z); a1[6] += bflo(v.w); a1[7] += bfhi(v.w);
        }
        if (e0 + 2 < dgc) {
            uint4 v = *(const uint4*)(data16 + (size_t)i2 * D + 8 * ln);
            a2[0] += bflo(v.x); a2[1] += bfhi(v.x); a2[2] += bflo(v.y); a2[3] += bfhi(v.y);
            a2[4] += bflo(v.z); a2[5] += bfhi(v.z); a2[6] += bflo(v.w); a2[7] += bfhi(v.w);
        }
        if (e0 + 3 < dgc) {
            uint4 v = *(const uint4*)(data16 + (size_t)i3 * D + 8 * ln);
            a3[0] += bflo(v.x); a3[1] += bfhi(v.x); a3[2] += bflo(v.y); a3[3] += bfhi(v.y);
            a3[4] += bflo(v.z); a3[5] += bfhi(v.z); a3[6] += bflo(v.w); a3[7] += bfhi(v.w);
        }
    }
    float s[8];
#pragma unroll
    for (int k = 0; k < 8; k++) s[k] = (a0[k] + a1[k]) + (a2[k] + a3[k]);
#pragma unroll
    for (int k = 0; k < 8; k++) s[k] += __shfl_xor(s[k], 8);

    if (par == 0) {
        float inv = dg > 0 ? 1.0f / (float)dg : 0.0f;
        float msk = dg > 0 ? 1.0f : 0.0f;
        float4 h0, h1;
        h0.x = (o0.x - s[0] * inv) * msk; h0.y = (o0.y - s[1] * inv) * msk;
        h0.z = (o0.z - s[2] * inv) * msk; h0.w = (o0.w - s[3] * inv) * msk;
        h1.x = (o1.x - s[4] * inv) * msk; h1.y = (o1.y - s[5] * inv) * msk;
        h1.z = (o1.z - s[6] * inv) * msk; h1.w = (o1.w - s[7] * inv) * msk;
        float4* hp = (float4*)(hbuf + node * D + 8 * ln);
        hp[0] = h0; hp[1] = h1;
    }
    __syncthreads();

    int w = tid >> 6;
#pragma unroll
    for (int tg = 0; tg < 4; tg++) {
        int t = w * 4 + tg;
        const float4* hrow = (const float4*)(hbuf + t * D);
        float acc = 0.f;
#pragma unroll
        for (int i = 0; i < 16; i++) {
            float4 hq = hrow[i];
            acc += hq.x * Wr[i].x + hq.y * Wr[i].y
                 + hq.z * Wr[i].z + hq.w * Wr[i].w;
        }
        int nn = nodeBase + t;
        float o = acc + out[(size_t)nn * D + lane];
        out[(size_t)nn * D + lane] = o > 0.f ? o : 0.f;
    }
}

extern "C" void kernel_launch(void* const* d_in, const int* in_sizes, int n_in,
                              void* d_out, int out_size, void* d_ws, size_t ws_size,
                              hipStream_t stream) {
    const float* data  = (const float*)d_in[0];
    const float* merge = (const float*)d_in[1];
    const int*   src   = (const int*)d_in[2];
    const int*   tgt   = (const int*)d_in[3];
    // d_in[4]=W_lin, d_in[5]=b_lin (cancels in lap), d_in[6]=W_tr, d_in[7]=b_tr
    const float* W_lin = (const float*)d_in[4];
    const float* W_tr  = (const float*)d_in[6];
    const float* b_tr  = (const float*)d_in[7];
    float* out = (float*)d_out;

    // Workspace: gCur[196*16 i32] (12.5 KB) | gPairs[196*16*384 u32] (4.8 MB)
    //            | srcs16[196*256*64 u16] (6.4 MB) | deg[196*256 i32]
    //            | data16[N*D bf16] (6.4 MB)          total ~18 MB
    char* ws = (char*)d_ws;
    size_t o = 0;
    int*            gCur   = (int*)(ws + o);            o += (size_t)COARSE * SHARDS * 4;
    unsigned int*   gPairs = (unsigned int*)(ws + o);   o += (size_t)COARSE * SHARDS * SCAP * 4;
    unsigned short* srcs16 = (unsigned short*)(ws + o); o += (size_t)COARSE * 256 * NODE_CAP * 2;
    int*            deg    = (int*)(ws + o);            o += (size_t)COARSE * 256 * 4;
    unsigned short* data16 = (unsigned short*)(ws + o); o += (size_t)N_NODES * D * 2;

    hipMemsetAsync(gCur, 0, (size_t)COARSE * SHARDS * 4, stream);

    k1_kernel<<<K1_BLOCKS, 256, 0, stream>>>(
        data, merge, src, tgt, W_tr, b_tr, data16, gCur, gPairs, out);

    fill_kernel<<<COARSE, 256, 0, stream>>>(gCur, gPairs, srcs16, deg);

    k2_kernel<<<BINS, 256, 0, stream>>>(
        data, data16, srcs16, deg, W_lin, out);
}

// Round 15
// 200.383 us; speedup vs baseline: 1.0096x; 1.0096x over previous
//
#include <hip/hip_runtime.h>

#define N_NODES 50000
#define N_EDGES 800000
#define D 64
#define COARSE 196           // coarse bins of 256 nodes (tgt>>8)
#define SHARDS 16            // reservation shards per bin (block b -> b&15)
#define SCAP 384             // per (bin,shard) capacity: mean 255 + 8 sigma
#define BINS 3125            // k2 bins of 16 nodes
#define BIN_NODES 16
#define NODE_CAP 64          // deg ~ Poisson(16); P(>64) ~ 1e-18
#define BROW 72              // u16 stride per node bucket in LDS (144 B)
#define KA_BLOCKS 391        // 2048 edges per block (last: 1280)
#define KA_EDGES 2048
#define FILL_BLOCKS 196
#define CVT_BLOCKS 3125
#define GEMV_BLOCKS 3125
#define MID_BLOCKS (FILL_BLOCKS + CVT_BLOCKS + GEMV_BLOCKS)

__device__ __forceinline__ unsigned int f2bf(float f) {
    unsigned int u = __builtin_bit_cast(unsigned int, f);
    return (u + 0x7fffu + ((u >> 16) & 1u)) >> 16;
}
__device__ __forceinline__ float bflo(unsigned int v) {
    return __builtin_bit_cast(float, v << 16);
}
__device__ __forceinline__ float bfhi(unsigned int v) {
    return __builtin_bit_cast(float, v & 0xffff0000u);
}

// ---------------------------------------------------------------------------
// KA (standalone this round -- MEASUREMENT: is this the 50 us pole?).
// Coarse binning, block-private clean writes, NO LDS edge staging (phase 3
// re-reads src/tgt from L2 instead of LDS -- removes 4096 LDS ops/block and
// the biggest LDS allocation; orthogonal to the falsified bin-count/shard
// theories).
// ---------------------------------------------------------------------------
__global__ __launch_bounds__(256) void ka_kernel(
        const int* __restrict__ src, const int* __restrict__ tgt,
        int* __restrict__ gCur, unsigned int* __restrict__ gPairs) {
    __shared__ int hist[COARSE], rbase[COARSE], cur2[COARSE];
    int b = blockIdx.x;
    int tid = threadIdx.x;
    int eb = b * KA_EDGES;
    int n = N_EDGES - eb; if (n > KA_EDGES) n = KA_EDGES;
    int shard = b & (SHARDS - 1);
    if (tid < COARSE) { hist[tid] = 0; cur2[tid] = 0; }
    __syncthreads();
    // phase 1: histogram (vectorized 2 edges/thread/iter)
    for (int i0 = tid * 2; i0 < n; i0 += 512) {
        uint2 tv = *(const uint2*)(tgt + eb + i0);
        atomicAdd(&hist[tv.x >> 8], 1);
        atomicAdd(&hist[tv.y >> 8], 1);
    }
    __syncthreads();
    // phase 2: sharded global reservation
    if (tid < COARSE && hist[tid] > 0)
        rbase[tid] = atomicAdd(&gCur[tid * SHARDS + shard], hist[tid]);
    __syncthreads();
    // phase 3: re-read edges (L2-hot) + scatter into reserved runs
    size_t segBase0 = (size_t)shard * SCAP;
    for (int i = tid; i < n; i += 256) {
        unsigned int t = (unsigned int)tgt[eb + i];
        unsigned int p = (t << 16) | (unsigned int)src[eb + i];
        int c = t >> 8;
        int pos = rbase[c] + atomicAdd(&cur2[c], 1);
        if (pos < SCAP)
            gPairs[(size_t)c * (SHARDS * SCAP) + segBase0 + pos] = p;
    }
}

// ---------------------------------------------------------------------------
// MID: fill + cvt + gemv, role-major (fill first: longest, lowest occupancy).
//  [0, FILL):  one block per coarse bin -> per-node global buckets
//    srcs16[node*64] + deg[node]; block owns its 32 KB region (clean writes).
//  [FILL,+CVT): data16 = bf16(data), RNE, coalesced.
//  [..,+GEMV):  out = merge @ W_tr^T + b_tr  (direct to d_out; k2 RMWs it)
// ---------------------------------------------------------------------------
__global__ __launch_bounds__(256) void mid_kernel(
        const float* __restrict__ data,
        const float* __restrict__ merge,
        const float* __restrict__ W_tr, const float* __restrict__ b_tr,
        const int* __restrict__ gCur,
        const unsigned int* __restrict__ gPairs,
        unsigned short* __restrict__ srcs16,
        int* __restrict__ deg,
        unsigned short* __restrict__ data16,
        float* __restrict__ outv) {
    int b = blockIdx.x;
    int tid = threadIdx.x;
    if (b < FILL_BLOCKS) {
        __shared__ int lcur[256];
        int c = b;
        lcur[tid] = 0;
        __syncthreads();
        for (int s = 0; s < SHARDS; s++) {
            int cnt = gCur[c * SHARDS + s]; if (cnt > SCAP) cnt = SCAP;
            const unsigned int* cp = gPairs + (size_t)c * (SHARDS * SCAP)
                                            + (size_t)s * SCAP;
            for (int i = tid; i < cnt; i += 256) {
                unsigned int p = cp[i];
                int tl = (p >> 16) & 255;
                int pos = atomicAdd(&lcur[tl], 1);
                if (pos < NODE_CAP)
                    srcs16[((size_t)c * 256 + tl) * NODE_CAP + pos] =
                        (unsigned short)(p & 0xffffu);
            }
        }
        __syncthreads();
        int node = c * 256 + tid;
        if (node < N_NODES) deg[node] = lcur[tid];
    } else if (b < FILL_BLOCKS + CVT_BLOCKS) {
        int i = (b - FILL_BLOCKS) * 256 + tid;   // float4 index
        float4 d = ((const float4*)data)[i];
        uint2 v;
        v.x = f2bf(d.x) | (f2bf(d.y) << 16);
        v.y = f2bf(d.z) | (f2bf(d.w) << 16);
        ((uint2*)data16)[i] = v;
    } else {
        int gb = b - FILL_BLOCKS - CVT_BLOCKS;
        int lane = tid & 63;
        int slot = tid >> 6;
        float4 Wr[16];
        const float4* wrow = (const float4*)(W_tr + (size_t)lane * D);
#pragma unroll
        for (int i = 0; i < 16; i++) Wr[i] = wrow[i];
        float bias = b_tr[lane];
        const int stride = GEMV_BLOCKS * 4;
        int r = gb * 4 + slot;
        float rv = merge[(size_t)r * D + lane];
        while (r < N_NODES) {
            int rn = r + stride;
            float rv_next = 0.f;
            if (rn < N_NODES) rv_next = merge[(size_t)rn * D + lane];
            float a0 = 0.f, a1 = 0.f, a2 = 0.f, a3 = 0.f;
#pragma unroll
            for (int i = 0; i < 16; i++) {
                a0 += __shfl(rv, 4 * i)     * Wr[i].x;
                a1 += __shfl(rv, 4 * i + 1) * Wr[i].y;
                a2 += __shfl(rv, 4 * i + 2) * Wr[i].z;
                a3 += __shfl(rv, 4 * i + 3) * Wr[i].w;
            }
            outv[(size_t)r * D + lane] = ((a0 + a1) + (a2 + a3)) + bias;
            rv = rv_next;
            r = rn;
        }
    }
}

// ---------------------------------------------------------------------------
// K2: one block per 16-node bin (unchanged, known-good).
// ---------------------------------------------------------------------------
__global__ __launch_bounds__(256) void k2_kernel(
        const float* __restrict__ data,
        const unsigned short* __restrict__ data16,
        const unsigned short* __restrict__ srcs16,
        const int* __restrict__ deg,
        const float* __restrict__ W_lin,
        float* __restrict__ out) {
    __shared__ __align__(16) unsigned short lbkt[BIN_NODES * BROW];
    __shared__ int lcur[BIN_NODES];
    __shared__ float hbuf[BIN_NODES * D];

    int tid = threadIdx.x;
    int lane = tid & 63;
    int bin = blockIdx.x;
    int nodeBase = bin * BIN_NODES;

    float4 Wr[16];
    const float4* wrow = (const float4*)(W_lin + (size_t)lane * D);
#pragma unroll
    for (int i = 0; i < 16; i++) Wr[i] = wrow[i];

    {
        int node = tid >> 4;
        int ln = tid & 15;
        uint2 w = ((const uint2*)(srcs16 + ((size_t)nodeBase + node) * NODE_CAP))[ln];
        ((uint2*)(lbkt + node * BROW))[ln] = w;
        if (tid < BIN_NODES) lcur[tid] = deg[nodeBase + tid];
    }
    __syncthreads();

    int G = tid >> 3;
    int ln = tid & 7;
    int node = G >> 1;
    int par = G & 1;
    int n = nodeBase + node;
    int dg = lcur[node];
    int dgc = dg < NODE_CAP ? dg : NODE_CAP;

    const float4* orow = (const float4*)(data + (size_t)n * D + 8 * ln);
    float4 o0 = orow[0], o1 = orow[1];

    float a0[8] = {0,0,0,0,0,0,0,0}, a1[8] = {0,0,0,0,0,0,0,0};
    float a2[8] = {0,0,0,0,0,0,0,0}, a3[8] = {0,0,0,0,0,0,0,0};
    const uint2* idxp = (const uint2*)(lbkt + node * BROW + par * 4);
    int nIt = (dgc + 7) >> 3;
    for (int it = 0; it < nIt; it++) {
        uint2 iw = idxp[it * 2];
        int e0 = it * 8 + par * 4;
        unsigned int i0 = iw.x & 0xffffu, i1 = iw.x >> 16;
        unsigned int i2 = iw.y & 0xffffu, i3 = iw.y >> 16;
        if (e0 < dgc) {
            uint4 v = *(const uint4*)(data16 + (size_t)i0 * D + 8 * ln);
            a0[0] += bflo(v.x); a0[1] += bfhi(v.x); a0[2] += bflo(v.y); a0[3] += bfhi(v.y);
            a0[4] += bflo(v.z); a0[5] += bfhi(v.z); a0[6] += bflo(v.w); a0[7] += bfhi(v.w);
        }
        if (e0 + 1 < dgc) {
            uint4 v = *(const uint4*)(data16 + (size_t)i1 * D + 8 * ln);
            a1[0] += bflo(v.x); a1[1] += bfhi(v.x); a1[2] += bflo(v.y); a1[3] += bfhi(v.y);
            a1[4] += bflo(v.z); a1[5] += bfhi(v.z); a1[6] += bflo(v.w); a1[7] += bfhi(v.w);
        }
        if (e0 + 2 < dgc) {
            uint4 v = *(const uint4*)(data16 + (size_t)i2 * D + 8 * ln);
            a2[0] += bflo(v.x); a2[1] += bfhi(v.x); a2[2] += bflo(v.y); a2[3] += bfhi(v.y);
            a2[4] += bflo(v.z); a2[5] += bfhi(v.z); a2[6] += bflo(v.w); a2[7] += bfhi(v.w);
        }
        if (e0 + 3 < dgc) {
            uint4 v = *(const uint4*)(data16 + (size_t)i3 * D + 8 * ln);
            a3[0] += bflo(v.x); a3[1] += bfhi(v.x); a3[2] += bflo(v.y); a3[3] += bfhi(v.y);
            a3[4] += bflo(v.z); a3[5] += bfhi(v.z); a3[6] += bflo(v.w); a3[7] += bfhi(v.w);
        }
    }
    float s[8];
#pragma unroll
    for (int k = 0; k < 8; k++) s[k] = (a0[k] + a1[k]) + (a2[k] + a3[k]);
#pragma unroll
    for (int k = 0; k < 8; k++) s[k] += __shfl_xor(s[k], 8);

    if (par == 0) {
        float inv = dg > 0 ? 1.0f / (float)dg : 0.0f;
        float msk = dg > 0 ? 1.0f : 0.0f;
        float4 h0, h1;
        h0.x = (o0.x - s[0] * inv) * msk; h0.y = (o0.y - s[1] * inv) * msk;
        h0.z = (o0.z - s[2] * inv) * msk; h0.w = (o0.w - s[3] * inv) * msk;
        h1.x = (o1.x - s[4] * inv) * msk; h1.y = (o1.y - s[5] * inv) * msk;
        h1.z = (o1.z - s[6] * inv) * msk; h1.w = (o1.w - s[7] * inv) * msk;
        float4* hp = (float4*)(hbuf + node * D + 8 * ln);
        hp[0] = h0; hp[1] = h1;
    }
    __syncthreads();

    int w = tid >> 6;
#pragma unroll
    for (int tg = 0; tg < 4; tg++) {
        int t = w * 4 + tg;
        const float4* hrow = (const float4*)(hbuf + t * D);
        float acc = 0.f;
#pragma unroll
        for (int i = 0; i < 16; i++) {
            float4 hq = hrow[i];
            acc += hq.x * Wr[i].x + hq.y * Wr[i].y
                 + hq.z * Wr[i].z + hq.w * Wr[i].w;
        }
        int nn = nodeBase + t;
        float o = acc + out[(size_t)nn * D + lane];
        out[(size_t)nn * D + lane] = o > 0.f ? o : 0.f;
    }
}

extern "C" void kernel_launch(void* const* d_in, const int* in_sizes, int n_in,
                              void* d_out, int out_size, void* d_ws, size_t ws_size,
                              hipStream_t stream) {
    const float* data  = (const float*)d_in[0];
    const float* merge = (const float*)d_in[1];
    const int*   src   = (const int*)d_in[2];
    const int*   tgt   = (const int*)d_in[3];
    // d_in[4]=W_lin, d_in[5]=b_lin (cancels in lap), d_in[6]=W_tr, d_in[7]=b_tr
    const float* W_lin = (const float*)d_in[4];
    const float* W_tr  = (const float*)d_in[6];
    const float* b_tr  = (const float*)d_in[7];
    float* out = (float*)d_out;

    char* ws = (char*)d_ws;
    size_t o = 0;
    int*            gCur   = (int*)(ws + o);            o += (size_t)COARSE * SHARDS * 4;
    unsigned int*   gPairs = (unsigned int*)(ws + o);   o += (size_t)COARSE * SHARDS * SCAP * 4;
    unsigned short* srcs16 = (unsigned short*)(ws + o); o += (size_t)COARSE * 256 * NODE_CAP * 2;
    int*            deg    = (int*)(ws + o);            o += (size_t)COARSE * 256 * 4;
    unsigned short* data16 = (unsigned short*)(ws + o); o += (size_t)N_NODES * D * 2;

    hipMemsetAsync(gCur, 0, (size_t)COARSE * SHARDS * 4, stream);

    ka_kernel<<<KA_BLOCKS, 256, 0, stream>>>(src, tgt, gCur, gPairs);

    mid_kernel<<<MID_BLOCKS, 256, 0, stream>>>(
        data, merge, W_tr, b_tr, gCur, gPairs, srcs16, deg, data16, out);

    k2_kernel<<<BINS, 256, 0, stream>>>(
        data, data16, srcs16, deg, W_lin, out);
}